// Round 1
// baseline (1802.250 us; speedup 1.0000x reference)
//
#include <hip/hip_runtime.h>
#include <math.h>

#define CDIM 256
#define NDIM 4096

// ---------------------------------------------------------------------------
// GEMM: Y[b,o,j] = sum_c W[o,c] * X[b,c,j] + bias[o]
// grid (NDIM/64, OD/64, B), block 256. 64x64 tile, 4x4 microtile, BK=16.
// ---------------------------------------------------------------------------
template <int OD>
__global__ __launch_bounds__(256) void gemm_wx(const float* __restrict__ W,
                                               const float* __restrict__ X,
                                               const float* __restrict__ bias,
                                               float* __restrict__ Y) {
  __shared__ float as[16][68];  // as[k][o]
  __shared__ float bs[16][68];  // bs[k][j]
  const int j0 = blockIdx.x * 64;
  const int o0 = blockIdx.y * 64;
  const int b = blockIdx.z;
  const float* Xb = X + (size_t)b * CDIM * NDIM;
  float* Yb = Y + (size_t)b * OD * NDIM;
  const int t = threadIdx.x;
  const int tx = t & 15, ty = t >> 4;
  const int ar = t >> 2, ak4 = (t & 3) << 2;   // A-tile loader coords
  const int bk = t >> 4, bj4 = (t & 15) << 2;  // B-tile loader coords
  float acc[4][4] = {};
  for (int k0 = 0; k0 < CDIM; k0 += 16) {
    __syncthreads();
    float4 av = *(const float4*)(W + (size_t)(o0 + ar) * CDIM + k0 + ak4);
    as[ak4 + 0][ar] = av.x;
    as[ak4 + 1][ar] = av.y;
    as[ak4 + 2][ar] = av.z;
    as[ak4 + 3][ar] = av.w;
    *(float4*)&bs[bk][bj4] =
        *(const float4*)(Xb + (size_t)(k0 + bk) * NDIM + j0 + bj4);
    __syncthreads();
#pragma unroll
    for (int k = 0; k < 16; ++k) {
      float a[4], bv[4];
#pragma unroll
      for (int i = 0; i < 4; ++i) a[i] = as[k][4 * ty + i];
#pragma unroll
      for (int j = 0; j < 4; ++j) bv[j] = bs[k][4 * tx + j];
#pragma unroll
      for (int i = 0; i < 4; ++i)
#pragma unroll
        for (int j = 0; j < 4; ++j) acc[i][j] = fmaf(a[i], bv[j], acc[i][j]);
    }
  }
#pragma unroll
  for (int i = 0; i < 4; ++i) {
    float bi = bias[o0 + 4 * ty + i];
    float4 r = {acc[i][0] + bi, acc[i][1] + bi, acc[i][2] + bi, acc[i][3] + bi};
    *(float4*)(Yb + (size_t)(o0 + 4 * ty + i) * NDIM + j0 + 4 * tx) = r;
  }
}

// ---------------------------------------------------------------------------
// Flash attention (fp32): per block: batch=blockIdx.y, 64 query cols m0..m0+63.
// Q,K,V are (256, 4096) c-major slices of qkv_ws. Online softmax over keys n.
// S[n][m] = (1/16) sum_c K[c,n] Q[c,m];  O[c][m] = sum_n V[c,n] P[n,m]
// ---------------------------------------------------------------------------
__global__ __launch_bounds__(256) void flash_attn(const float* __restrict__ qkv,
                                                  float* __restrict__ o_ws) {
  __shared__ float ks[32][64];   // K chunk [c-local][n]
  __shared__ float qs[32][64];   // Q chunk [c-local][m]
  __shared__ float ps[64][68];   // P tile  [n][m]
  __shared__ float vs[CDIM][20]; // V chunk [c][n-local(16)]
  __shared__ float red[16][64];  // column reductions
  __shared__ float mstate[64], lstate[64], alphas[64];

  const int b = blockIdx.y;
  const int m0 = blockIdx.x * 64;
  const int t = threadIdx.x;
  const int tm = t & 15;  // column group: m cols 4*tm..4*tm+3 (both phases)
  const int tn = t >> 4;  // S-phase: n rows 4*tn..; PV-phase: c rows tn+16*ii
  const float* Q = qkv + (size_t)b * 3 * CDIM * NDIM;
  const float* K = Q + (size_t)CDIM * NDIM;
  const float* V = K + (size_t)CDIM * NDIM;

  if (t < 64) {
    mstate[t] = -1e30f;
    lstate[t] = 0.f;
  }

  float oacc[16][4] = {};  // O[c = tn + 16*ii][m = 4*tm + j]

  const int lr = t >> 4;          // loader row 0..15
  const int lc4 = (t & 15) << 2;  // loader col 0,4,..,60

  for (int n0 = 0; n0 < NDIM; n0 += 64) {
    // ---- S = K_tile^T Q_tile (reduction over c in chunks of 32) ----
    float sacc[4][4] = {};
    for (int cc = 0; cc < CDIM; cc += 32) {
      __syncthreads();
#pragma unroll
      for (int r = 0; r < 2; ++r) {
        int row = lr + 16 * r;
        *(float4*)&ks[row][lc4] =
            *(const float4*)(K + (size_t)(cc + row) * NDIM + n0 + lc4);
        *(float4*)&qs[row][lc4] =
            *(const float4*)(Q + (size_t)(cc + row) * NDIM + m0 + lc4);
      }
      __syncthreads();
#pragma unroll
      for (int k = 0; k < 32; ++k) {
        float a[4], bv[4];
#pragma unroll
        for (int i = 0; i < 4; ++i) a[i] = ks[k][4 * tn + i];
#pragma unroll
        for (int j = 0; j < 4; ++j) bv[j] = qs[k][4 * tm + j];
#pragma unroll
        for (int i = 0; i < 4; ++i)
#pragma unroll
          for (int j = 0; j < 4; ++j)
            sacc[i][j] = fmaf(a[i], bv[j], sacc[i][j]);
      }
    }
    const float scale = 0.0625f;  // 1/sqrt(256)

    // ---- online softmax over n (rows), per column m ----
    // local per-column max of this thread's 4 rows
    {
      float4 cm;
      cm.x = fmaxf(fmaxf(sacc[0][0], sacc[1][0]), fmaxf(sacc[2][0], sacc[3][0])) * scale;
      cm.y = fmaxf(fmaxf(sacc[0][1], sacc[1][1]), fmaxf(sacc[2][1], sacc[3][1])) * scale;
      cm.z = fmaxf(fmaxf(sacc[0][2], sacc[1][2]), fmaxf(sacc[2][2], sacc[3][2])) * scale;
      cm.w = fmaxf(fmaxf(sacc[0][3], sacc[1][3]), fmaxf(sacc[2][3], sacc[3][3])) * scale;
      *(float4*)&red[tn][4 * tm] = cm;
    }
    __syncthreads();
    if (t < 64) {
      float tmax = red[0][t];
#pragma unroll
      for (int i = 1; i < 16; ++i) tmax = fmaxf(tmax, red[i][t]);
      float mo = mstate[t];
      float mn = fmaxf(mo, tmax);
      mstate[t] = mn;
      alphas[t] = __expf(mo - mn);
    }
    __syncthreads();
    // p = exp(s*scale - m_new); write P tile; per-column partial sums
    {
      float mncol[4];
#pragma unroll
      for (int j = 0; j < 4; ++j) mncol[j] = mstate[4 * tm + j];
      float ls0 = 0.f, ls1 = 0.f, ls2 = 0.f, ls3 = 0.f;
#pragma unroll
      for (int i = 0; i < 4; ++i) {
        float4 pv;
        pv.x = __expf(sacc[i][0] * scale - mncol[0]);
        pv.y = __expf(sacc[i][1] * scale - mncol[1]);
        pv.z = __expf(sacc[i][2] * scale - mncol[2]);
        pv.w = __expf(sacc[i][3] * scale - mncol[3]);
        ls0 += pv.x; ls1 += pv.y; ls2 += pv.z; ls3 += pv.w;
        *(float4*)&ps[4 * tn + i][4 * tm] = pv;
      }
      float4 lsv = {ls0, ls1, ls2, ls3};
      *(float4*)&red[tn][4 * tm] = lsv;
    }
    __syncthreads();
    if (t < 64) {
      float s_ = 0.f;
#pragma unroll
      for (int i = 0; i < 16; ++i) s_ += red[i][t];
      lstate[t] = lstate[t] * alphas[t] + s_;
    }
    // rescale O accumulator by alpha (per column)
    {
      float al[4];
#pragma unroll
      for (int j = 0; j < 4; ++j) al[j] = alphas[4 * tm + j];
#pragma unroll
      for (int ii = 0; ii < 16; ++ii)
#pragma unroll
        for (int j = 0; j < 4; ++j) oacc[ii][j] *= al[j];
    }
    // ---- O += V_tile * P (n-chunks of 16) ----
    for (int nn = 0; nn < 64; nn += 16) {
      __syncthreads();
#pragma unroll
      for (int r = 0; r < 4; ++r) {
        int c = (t >> 2) + 64 * r;
        *(float4*)&vs[c][(t & 3) << 2] =
            *(const float4*)(V + (size_t)c * NDIM + n0 + nn + ((t & 3) << 2));
      }
      __syncthreads();
#pragma unroll
      for (int n4 = 0; n4 < 16; n4 += 4) {
        float4 pr[4];
#pragma unroll
        for (int kk = 0; kk < 4; ++kk)
          pr[kk] = *(const float4*)&ps[nn + n4 + kk][4 * tm];
#pragma unroll
        for (int ii = 0; ii < 16; ++ii) {
          int c = tn + 16 * ii;
          float4 vv = *(const float4*)&vs[c][n4];
          oacc[ii][0] = fmaf(vv.x, pr[0].x, oacc[ii][0]);
          oacc[ii][1] = fmaf(vv.x, pr[0].y, oacc[ii][1]);
          oacc[ii][2] = fmaf(vv.x, pr[0].z, oacc[ii][2]);
          oacc[ii][3] = fmaf(vv.x, pr[0].w, oacc[ii][3]);
          oacc[ii][0] = fmaf(vv.y, pr[1].x, oacc[ii][0]);
          oacc[ii][1] = fmaf(vv.y, pr[1].y, oacc[ii][1]);
          oacc[ii][2] = fmaf(vv.y, pr[1].z, oacc[ii][2]);
          oacc[ii][3] = fmaf(vv.y, pr[1].w, oacc[ii][3]);
          oacc[ii][0] = fmaf(vv.z, pr[2].x, oacc[ii][0]);
          oacc[ii][1] = fmaf(vv.z, pr[2].y, oacc[ii][1]);
          oacc[ii][2] = fmaf(vv.z, pr[2].z, oacc[ii][2]);
          oacc[ii][3] = fmaf(vv.z, pr[2].w, oacc[ii][3]);
          oacc[ii][0] = fmaf(vv.w, pr[3].x, oacc[ii][0]);
          oacc[ii][1] = fmaf(vv.w, pr[3].y, oacc[ii][1]);
          oacc[ii][2] = fmaf(vv.w, pr[3].z, oacc[ii][2]);
          oacc[ii][3] = fmaf(vv.w, pr[3].w, oacc[ii][3]);
        }
      }
    }
  }

  // ---- finalize: O / l ----
  __syncthreads();
  float linv[4];
#pragma unroll
  for (int j = 0; j < 4; ++j) linv[j] = 1.0f / lstate[4 * tm + j];
  float* Ob = o_ws + (size_t)b * CDIM * NDIM;
#pragma unroll
  for (int ii = 0; ii < 16; ++ii) {
    int c = tn + 16 * ii;
    float4 r = {oacc[ii][0] * linv[0], oacc[ii][1] * linv[1],
                oacc[ii][2] * linv[2], oacc[ii][3] * linv[3]};
    *(float4*)(Ob + (size_t)c * NDIM + m0 + 4 * tm) = r;
  }
}

// ---------------------------------------------------------------------------
extern "C" void kernel_launch(void* const* d_in, const int* in_sizes, int n_in,
                              void* d_out, int out_size, void* d_ws,
                              size_t ws_size, hipStream_t stream) {
  const float* x = (const float*)d_in[0];
  const float* qkv_w = (const float*)d_in[1];
  const float* qkv_b = (const float*)d_in[2];
  const float* out_w = (const float*)d_in[3];
  const float* out_b = (const float*)d_in[4];
  float* out = (float*)d_out;

  float* qkv_ws = (float*)d_ws;                       // 4*768*4096 f32 = 48 MB
  float* o_ws = qkv_ws + (size_t)4 * 768 * NDIM;      // 4*256*4096 f32 = 16 MB

  dim3 blk(256);
  // qkv projection: (768 x 256) x (256 x 4096) per batch
  gemm_wx<768><<<dim3(NDIM / 64, 768 / 64, 4), blk, 0, stream>>>(
      qkv_w, x, qkv_b, qkv_ws);
  // attention
  flash_attn<<<dim3(NDIM / 64, 4), blk, 0, stream>>>(qkv_ws, o_ws);
  // output projection: (256 x 256) x (256 x 4096) per batch -> d_out
  gemm_wx<256><<<dim3(NDIM / 64, 256 / 64, 4), blk, 0, stream>>>(
      out_w, o_ws, out_b, out);
}

// Round 2
// 320.329 us; speedup vs baseline: 5.6263x; 5.6263x over previous
//
#include <hip/hip_runtime.h>

typedef unsigned short u16;
typedef __attribute__((ext_vector_type(8))) short short8;   // 8 x bf16 MFMA frag
typedef __attribute__((ext_vector_type(4))) short short4v;  // 4 x bf16 pack
typedef __attribute__((ext_vector_type(4))) float f32x4;

#define MFMA_BF16 __builtin_amdgcn_mfma_f32_16x16x32_bf16

#define NSEQ 4096
#define CD 256

__device__ __forceinline__ u16 f2bf(float f) {
  unsigned u = __float_as_uint(f);
  u += 0x7fffu + ((u >> 16) & 1u);  // RNE
  return (u16)(u >> 16);
}

// ---------------------------------------------------------------------------
// cast weights fp32 -> bf16
// ---------------------------------------------------------------------------
__global__ void cast_w(const float* __restrict__ qkv_w,
                       const float* __restrict__ out_w, u16* __restrict__ wq,
                       u16* __restrict__ wo) {
  int idx = blockIdx.x * 256 + threadIdx.x;
  if (idx < 768 * CD) wq[idx] = f2bf(qkv_w[idx]);
  if (idx < CD * CD) wo[idx] = f2bf(out_w[idx]);
}

// ---------------------------------------------------------------------------
// transpose-cast x: (b, 256, 4096) f32 -> x_t (b, 4096, 256) bf16
// ---------------------------------------------------------------------------
__global__ __launch_bounds__(256) void xpose(const float* __restrict__ x,
                                             u16* __restrict__ x_t) {
  __shared__ float tile[64][65];
  const int t = threadIdx.x;
  const int b = blockIdx.z;
  const int n0 = blockIdx.x * 64, c0 = blockIdx.y * 64;
  const float* xb = x + (size_t)b * CD * NSEQ;
  const int cr = t >> 4, nc4 = (t & 15) * 4;
#pragma unroll
  for (int i = 0; i < 4; ++i) {
    int c = cr + 16 * i;
    float4 v = *(const float4*)(xb + (size_t)(c0 + c) * NSEQ + n0 + nc4);
    tile[c][nc4 + 0] = v.x;
    tile[c][nc4 + 1] = v.y;
    tile[c][nc4 + 2] = v.z;
    tile[c][nc4 + 3] = v.w;
  }
  __syncthreads();
  const int n = t & 63, cc = (t >> 6) * 16;
  u16* dst = x_t + (size_t)b * NSEQ * CD + (size_t)(n0 + n) * CD + c0 + cc;
#pragma unroll
  for (int j = 0; j < 4; ++j) {
    short4v pv;
#pragma unroll
    for (int r = 0; r < 4; ++r) pv[r] = (short)f2bf(tile[cc + 4 * j + r][n]);
    *(short4v*)(dst + 4 * j) = pv;
  }
}

// ---------------------------------------------------------------------------
// QKV projection: D[o][n] = sum_c W[o][c] * x_t[n][c] + bias[o]
// cache-direct MFMA (no LDS). Epilogue writes q_t/k_t (n,c) and v (c,n) bf16.
// grid (64, 12, 4), block 256 (4 waves; wave w owns o-rows o0+16w..+15).
// ---------------------------------------------------------------------------
__global__ __launch_bounds__(256) void qkv_gemm(
    const u16* __restrict__ wq, const float* __restrict__ qkv_b,
    const u16* __restrict__ x_t, u16* __restrict__ q_t, u16* __restrict__ k_t,
    u16* __restrict__ v_) {
  const int t = threadIdx.x, w = t >> 6, lane = t & 63;
  const int lm = lane & 15, q4 = lane >> 4;
  const int b = blockIdx.z;
  const int n0 = blockIdx.x * 64;
  const int o0 = blockIdx.y * 64 + w * 16;
  const u16* xb = x_t + (size_t)b * NSEQ * CD;
  f32x4 zero4 = {0.f, 0.f, 0.f, 0.f};
  f32x4 acc[4] = {zero4, zero4, zero4, zero4};
#pragma unroll
  for (int kc = 0; kc < 8; ++kc) {
    short8 af = *(const short8*)(wq + (size_t)(o0 + lm) * CD + kc * 32 + q4 * 8);
#pragma unroll
    for (int ns = 0; ns < 4; ++ns) {
      short8 bf =
          *(const short8*)(xb + (size_t)(n0 + 16 * ns + lm) * CD + kc * 32 + q4 * 8);
      acc[ns] = MFMA_BF16(af, bf, acc[ns], 0, 0, 0);
    }
  }
  const int og0 = o0 + 4 * q4;  // o for reg r is og0 + r
  float bias[4];
#pragma unroll
  for (int r = 0; r < 4; ++r) bias[r] = qkv_b[og0 + r];
  const int otype = blockIdx.y >> 2;  // 0=Q, 1=K, 2=V
  if (otype < 2) {
    u16* dst = (otype == 0 ? q_t : k_t) + (size_t)b * NSEQ * CD;
    const int c0 = og0 - otype * CD;
#pragma unroll
    for (int ns = 0; ns < 4; ++ns) {
      int n = n0 + 16 * ns + lm;
      short4v pv;
#pragma unroll
      for (int r = 0; r < 4; ++r) pv[r] = (short)f2bf(acc[ns][r] + bias[r]);
      *(short4v*)(dst + (size_t)n * CD + c0) = pv;
    }
  } else {
    u16* dst = v_ + (size_t)b * CD * NSEQ;
#pragma unroll
    for (int ns = 0; ns < 4; ++ns)
#pragma unroll
      for (int r = 0; r < 4; ++r)
        dst[(size_t)(og0 - 512 + r) * NSEQ + n0 + 16 * ns + lm] =
            f2bf(acc[ns][r] + bias[r]);
  }
}

// ---------------------------------------------------------------------------
// Flash attention, bf16 MFMA.
// Block: 64 query cols (m), 4 waves x m=16. n-tile = 64 keys.
// S[n][m] = sum_c K_t[n][c] Q_t[m][c]  (A=K frag, B=Q frag from regs)
// O[m][c] = sum_n P[n][m] V[c][n]      (A=P via LDS, B=V frag)
// LDS K/V tiles XOR-swizzled at 16B granularity to break bank conflicts.
// XCD swizzle: 2 XCDs per batch -> K+V (4MB) fits per-XCD L2.
// ---------------------------------------------------------------------------
__global__ __launch_bounds__(256, 2) void flash_mfma(
    const u16* __restrict__ q_t, const u16* __restrict__ k_t,
    const u16* __restrict__ v_, u16* __restrict__ o_t) {
  __shared__ u16 __align__(16) Kls[64 * 256];   // [n][c ^ swz]
  __shared__ u16 __align__(16) Vls[256 * 64];   // [c][n ^ swz]
  __shared__ u16 __align__(16) Pls[4][16 * 72]; // per-wave [m][n], stride 72

  const int t = threadIdx.x;
  const int w = t >> 6;
  const int lane = t & 63;
  const int lm = lane & 15;
  const int q4 = lane >> 4;

  // XCD-aware remap: xcd = blockIdx % 8 (typical); 2 XCDs per batch.
  const int linear = blockIdx.x;
  const int xcd = linear & 7, slot = linear >> 3;
  const int b = xcd >> 1;
  const int mblk = slot + 32 * (xcd & 1);
  const int m0 = mblk * 64 + w * 16;

  const u16* Qb = q_t + (size_t)b * NSEQ * CD;
  const u16* Kb = k_t + (size_t)b * NSEQ * CD;
  const u16* Vb = v_ + (size_t)b * CD * NSEQ;

  // Q fragments in registers for the whole kernel (B-operand, K=256 -> 8 frags)
  short8 qf[8];
#pragma unroll
  for (int kc = 0; kc < 8; ++kc)
    qf[kc] = *(const short8*)(Qb + (size_t)(m0 + lm) * CD + kc * 32 + q4 * 8);

  const float cf = 0.0625f * 1.4426950408889634f;  // (1/sqrt(256)) * log2(e)
  float mstate = -3.0e38f;
  float lpart = 0.f;
  f32x4 zero4 = {0.f, 0.f, 0.f, 0.f};
  f32x4 oacc[16];
#pragma unroll
  for (int i = 0; i < 16; ++i) oacc[i] = zero4;

  u16* Pw = &Pls[w][0];

  for (int n0 = 0; n0 < NSEQ; n0 += 64) {
    __syncthreads();
    // ---- stage K (64n x 256c) and V (256c x 64n) tiles, swizzled ----
#pragma unroll
    for (int i = 0; i < 8; ++i) {
      int idx = t + 256 * i;
      int kr = idx >> 5, kc8 = idx & 31;
      short8 kv = *(const short8*)(Kb + (size_t)(n0 + kr) * CD + kc8 * 8);
      *(short8*)(Kls + kr * 256 + ((kc8 ^ (kr & 7)) * 8)) = kv;
      int vr = idx >> 3, vn8 = idx & 7;
      short8 vv = *(const short8*)(Vb + (size_t)vr * NSEQ + n0 + vn8 * 8);
      *(short8*)(Vls + vr * 64 + ((vn8 ^ (vr & 7)) * 8)) = vv;
    }
    __syncthreads();

    // ---- S = K . Q^T : 4 n-subtiles x 8 k-chunks ----
    f32x4 sacc[4];
#pragma unroll
    for (int s = 0; s < 4; ++s) sacc[s] = zero4;
#pragma unroll
    for (int kc = 0; kc < 8; ++kc) {
#pragma unroll
      for (int s = 0; s < 4; ++s) {
        int row = 16 * s + lm;
        short8 af =
            *(const short8*)(Kls + row * 256 + (((kc << 2) | q4) ^ (row & 7)) * 8);
        sacc[s] = MFMA_BF16(af, qf[kc], sacc[s], 0, 0, 0);
      }
    }

    // ---- online softmax (per m = lane&15; quads share via shfl_xor) ----
    float rmax = -3.0e38f;
#pragma unroll
    for (int s = 0; s < 4; ++s)
#pragma unroll
      for (int r = 0; r < 4; ++r) rmax = fmaxf(rmax, sacc[s][r]);
    rmax = fmaxf(rmax, __shfl_xor(rmax, 16));
    rmax = fmaxf(rmax, __shfl_xor(rmax, 32));
    float mnew = fmaxf(mstate, rmax * cf);
    float alpha = exp2f(mstate - mnew);
    mstate = mnew;
    float ls = 0.f;
#pragma unroll
    for (int s = 0; s < 4; ++s) {
      short4v pv;
#pragma unroll
      for (int r = 0; r < 4; ++r) {
        float p = exp2f(sacc[s][r] * cf - mnew);
        ls += p;
        pv[r] = (short)f2bf(p);
      }
      // lane holds S[n = 16s + 4*q4 + r][m = lm] -> P_lds[m][n]
      *(short4v*)(Pw + lm * 72 + s * 16 + q4 * 4) = pv;
    }
    lpart = lpart * alpha + ls;
    // rescale O accumulator: reg r has m = 4*q4 + r
    float ar[4];
#pragma unroll
    for (int r = 0; r < 4; ++r) ar[r] = __shfl(alpha, 4 * q4 + r);
#pragma unroll
    for (int cs = 0; cs < 16; ++cs)
#pragma unroll
      for (int r = 0; r < 4; ++r) oacc[cs][r] *= ar[r];

    // ---- O += P^T . V : 2 n-chunks x 16 c-subtiles ----
#pragma unroll
    for (int nc = 0; nc < 2; ++nc) {
      short8 pf = *(const short8*)(Pw + lm * 72 + nc * 32 + q4 * 8);
#pragma unroll
      for (int cs = 0; cs < 16; ++cs) {
        int c = 16 * cs + lm;
        short8 vf =
            *(const short8*)(Vls + c * 64 + (((nc << 2) | q4) ^ (c & 7)) * 8);
        oacc[cs] = MFMA_BF16(pf, vf, oacc[cs], 0, 0, 0);
      }
    }
  }

  // ---- finalize: O /= l ; store o_t (n, c) bf16 ----
  float lt = lpart;
  lt += __shfl_xor(lt, 16);
  lt += __shfl_xor(lt, 32);
  float inv[4];
#pragma unroll
  for (int r = 0; r < 4; ++r) inv[r] = 1.0f / __shfl(lt, 4 * q4 + r);
  u16* Ob = o_t + (size_t)b * NSEQ * CD;
#pragma unroll
  for (int cs = 0; cs < 16; ++cs)
#pragma unroll
    for (int r = 0; r < 4; ++r)
      Ob[(size_t)(m0 + 4 * q4 + r) * CD + 16 * cs + lm] =
          f2bf(oacc[cs][r] * inv[r]);
}

// ---------------------------------------------------------------------------
// out projection: out[b][o][n] = sum_c Wo[o][c] * o_t[n][c] + out_b[o] (f32)
// grid (64, 4, 4), block 256.
// ---------------------------------------------------------------------------
__global__ __launch_bounds__(256) void out_gemm(const u16* __restrict__ wo,
                                                const float* __restrict__ out_b,
                                                const u16* __restrict__ o_t,
                                                float* __restrict__ out) {
  const int t = threadIdx.x, w = t >> 6, lane = t & 63;
  const int lm = lane & 15, q4 = lane >> 4;
  const int b = blockIdx.z;
  const int n0 = blockIdx.x * 64;
  const int o0 = blockIdx.y * 64 + w * 16;
  const u16* ob_t = o_t + (size_t)b * NSEQ * CD;
  f32x4 zero4 = {0.f, 0.f, 0.f, 0.f};
  f32x4 acc[4] = {zero4, zero4, zero4, zero4};
#pragma unroll
  for (int kc = 0; kc < 8; ++kc) {
    short8 af = *(const short8*)(wo + (size_t)(o0 + lm) * CD + kc * 32 + q4 * 8);
#pragma unroll
    for (int ns = 0; ns < 4; ++ns) {
      short8 bf =
          *(const short8*)(ob_t + (size_t)(n0 + 16 * ns + lm) * CD + kc * 32 + q4 * 8);
      acc[ns] = MFMA_BF16(af, bf, acc[ns], 0, 0, 0);
    }
  }
  const int og0 = o0 + 4 * q4;
  float bv[4];
#pragma unroll
  for (int r = 0; r < 4; ++r) bv[r] = out_b[og0 + r];
#pragma unroll
  for (int ns = 0; ns < 4; ++ns)
#pragma unroll
    for (int r = 0; r < 4; ++r)
      out[((size_t)b * CD + og0 + r) * NSEQ + n0 + 16 * ns + lm] =
          acc[ns][r] + bv[r];
}

// ---------------------------------------------------------------------------
extern "C" void kernel_launch(void* const* d_in, const int* in_sizes, int n_in,
                              void* d_out, int out_size, void* d_ws,
                              size_t ws_size, hipStream_t stream) {
  const float* x = (const float*)d_in[0];
  const float* qkv_w = (const float*)d_in[1];
  const float* qkv_b = (const float*)d_in[2];
  const float* out_w = (const float*)d_in[3];
  const float* out_b = (const float*)d_in[4];
  float* out = (float*)d_out;

  const size_t SZ = (size_t)4 * NSEQ * CD;  // elems per (b,4096,256) bf16 tensor
  u16* x_t = (u16*)d_ws;
  u16* q_t = x_t + SZ;
  u16* k_t = q_t + SZ;
  u16* v_ = k_t + SZ;
  u16* o_t = v_ + SZ;
  u16* wq = o_t + SZ;
  u16* wo = wq + 768 * CD;

  dim3 blk(256);
  cast_w<<<dim3(768), blk, 0, stream>>>(qkv_w, out_w, wq, wo);
  xpose<<<dim3(64, 4, 4), blk, 0, stream>>>(x, x_t);
  qkv_gemm<<<dim3(64, 12, 4), blk, 0, stream>>>(wq, qkv_b, x_t, q_t, k_t, v_);
  flash_mfma<<<dim3(256), blk, 0, stream>>>(q_t, k_t, v_, o_t);
  out_gemm<<<dim3(64, 4, 4), blk, 0, stream>>>(wo, out_b, o_t, out);
}

// Round 6
// 273.015 us; speedup vs baseline: 6.6013x; 1.1733x over previous
//
#include <hip/hip_runtime.h>

typedef unsigned short u16;
typedef unsigned int u32;
typedef __attribute__((ext_vector_type(8))) short short8;   // 8 x bf16 frag
typedef __attribute__((ext_vector_type(4))) short short4v;  // 4 x bf16 pack
typedef __attribute__((ext_vector_type(16))) float f32x16;  // 32x32 acc

#define MFMA32 __builtin_amdgcn_mfma_f32_32x32x16_bf16

#define NSEQ 4096
#define CD 256
// (1/sqrt(256)) * log2(e) = 0.0625 * 1.4426950408889634  -- EXACT.
#define CF 0.09016844005556021f

__device__ __forceinline__ u16 f2bf(float f) {
  u32 u = __float_as_uint(f);
  u += 0x7fffu + ((u >> 16) & 1u);  // RNE
  return (u16)(u >> 16);
}
// async global -> LDS DMA, 16B per lane; LDS dest = wave-uniform base + lane*16
__device__ __forceinline__ void async16(const void* g, void* l) {
  __builtin_amdgcn_global_load_lds(
      (const __attribute__((address_space(1))) u32*)g,
      (__attribute__((address_space(3))) u32*)l, 16, 0, 0);
}

// ---------------------------------------------------------------------------
// cast weights fp32 -> bf16
// ---------------------------------------------------------------------------
__global__ void cast_w(const float* __restrict__ qkv_w,
                       const float* __restrict__ out_w, u16* __restrict__ wq,
                       u16* __restrict__ wo) {
  int idx = blockIdx.x * 256 + threadIdx.x;
  if (idx < 768 * CD) wq[idx] = f2bf(qkv_w[idx]);
  if (idx < CD * CD) wo[idx] = f2bf(out_w[idx]);
}

// ---------------------------------------------------------------------------
// transpose-cast x: (b, 256, 4096) f32 -> x_t (b, 4096, 256) bf16
// ---------------------------------------------------------------------------
__global__ __launch_bounds__(256) void xpose(const float* __restrict__ x,
                                             u16* __restrict__ x_t) {
  __shared__ float tile[64][65];
  const int t = threadIdx.x;
  const int b = blockIdx.z;
  const int n0 = blockIdx.x * 64, c0 = blockIdx.y * 64;
  const float* xb = x + (size_t)b * CD * NSEQ;
  const int cr = t >> 4, nc4 = (t & 15) * 4;
#pragma unroll
  for (int i = 0; i < 4; ++i) {
    int c = cr + 16 * i;
    float4 v = *(const float4*)(xb + (size_t)(c0 + c) * NSEQ + n0 + nc4);
    tile[c][nc4 + 0] = v.x;
    tile[c][nc4 + 1] = v.y;
    tile[c][nc4 + 2] = v.z;
    tile[c][nc4 + 3] = v.w;
  }
  __syncthreads();
  const int n = t & 63, cc = (t >> 6) * 16;
  u16* dst = x_t + (size_t)b * NSEQ * CD + (size_t)(n0 + n) * CD + c0 + cc;
#pragma unroll
  for (int j = 0; j < 4; ++j) {
    short4v pv;
#pragma unroll
    for (int r = 0; r < 4; ++r) pv[r] = (short)f2bf(tile[cc + 4 * j + r][n]);
    *(short4v*)(dst + 4 * j) = pv;
  }
}

// ---------------------------------------------------------------------------
// QKV projection, 32x32x16 MFMA, LDS-staged W and X tiles (XOR-swizzled, DMA).
// Single-shot staging (one barrier, no LDS reuse -> no WAR hazard).
// D[o][n] = sum_c W[o][c] x_t[n][c] + bias. grid (64, 12, 4), block 256.
// ---------------------------------------------------------------------------
__global__ __launch_bounds__(256, 2) void qkv_gemm2(
    const u16* __restrict__ wq, const float* __restrict__ qkv_b,
    const u16* __restrict__ x_t, u16* __restrict__ q_t, u16* __restrict__ k_t,
    u16* __restrict__ v_) {
  __shared__ u16 __align__(16) Wls[64 * 256];
  __shared__ u16 __align__(16) Bls[64 * 256];
  const int t = threadIdx.x, w = t >> 6, lane = t & 63;
  const int l31 = lane & 31, l5 = lane >> 5;
  const int oh = w & 1, nh2 = w >> 1;
  const int n0 = blockIdx.x * 64, o0 = blockIdx.y * 64, b = blockIdx.z;
  const u16* Xb = x_t + (size_t)b * NSEQ * CD;
#pragma unroll
  for (int j = 0; j < 8; ++j) {
    int r = w * 16 + j * 2 + l5;
    async16(wq + (size_t)(o0 + r) * CD + ((l31 ^ (r & 7)) * 8),
            Wls + (w * 16 + j * 2) * 256);
    async16(Xb + (size_t)(n0 + r) * CD + ((l31 ^ (r & 7)) * 8),
            Bls + (w * 16 + j * 2) * 256);
  }
  __builtin_amdgcn_s_waitcnt(0);
  __syncthreads();
  f32x16 acc;
#pragma unroll
  for (int i = 0; i < 16; ++i) acc[i] = 0.f;
  const int ra = oh * 32 + l31, rb = nh2 * 32 + l31;
#pragma unroll
  for (int kc = 0; kc < 16; ++kc) {
    short8 a = *(const short8*)(Wls + ra * 256 + (((kc * 2 + l5) ^ (ra & 7)) * 8));
    short8 bb = *(const short8*)(Bls + rb * 256 + (((kc * 2 + l5) ^ (rb & 7)) * 8));
    acc = MFMA32(a, bb, acc, 0, 0, 0);
  }
  const int n_g = n0 + nh2 * 32 + l31;
  const int otype = blockIdx.y >> 2;  // 0=Q 1=K 2=V
  if (otype < 2) {
    u16* dst = (otype == 0 ? q_t : k_t) + (size_t)b * NSEQ * CD + (size_t)n_g * CD;
    const int cb0 = o0 - otype * 256 + oh * 32;
#pragma unroll
    for (int g = 0; g < 4; ++g) {
      float4 bv = *(const float4*)(qkv_b + o0 + oh * 32 + g * 8 + l5 * 4);
      const float* bp = (const float*)&bv;
      short4v pk;
#pragma unroll
      for (int r = 0; r < 4; ++r) pk[r] = (short)f2bf(acc[g * 4 + r] + bp[r]);
      *(short4v*)(dst + cb0 + g * 8 + l5 * 4) = pk;
    }
  } else {
    u16* dst = v_ + (size_t)b * CD * NSEQ;
#pragma unroll
    for (int g = 0; g < 4; ++g) {
      float4 bv = *(const float4*)(qkv_b + o0 + oh * 32 + g * 8 + l5 * 4);
      const float* bp = (const float*)&bv;
#pragma unroll
      for (int r = 0; r < 4; ++r) {
        int c = o0 - 512 + oh * 32 + g * 8 + l5 * 4 + r;
        dst[(size_t)c * NSEQ + n_g] = f2bf(acc[g * 4 + r] + bp[r]);
      }
    }
  }
}

// ---------------------------------------------------------------------------
// Flash attention, 32x32x16 MFMA, DOUBLE-BUFFERED K/V DMA staging.
// grid 256, block 256 (4 waves). Wave (nh=w&1, mh=w>>1):
//   S-phase : S[n-half nh (32)][m-half mh (32)], K=256.  D col = m = lane&31.
//   PV-phase: O[c-half nh (128)][m-half mh (32)] over n-tile 64. D col = m.
// DMA for tile t+1 targets buf[(t+1)&1] while compute reads buf[t&1] -> the
// write-after-read hazard that raced in R5 is structurally impossible.
// Barriers/tile: top drain (waitcnt+sync), B2 (pmax), B3 (psum/P).
// ---------------------------------------------------------------------------
__global__ __launch_bounds__(256) void flash4(const u16* __restrict__ q_t,
                                              const u16* __restrict__ k_t,
                                              const u16* __restrict__ v_,
                                              u16* __restrict__ o_t) {
  __shared__ u16 __align__(16) Kls[2][64 * 256];  // [buf][n][c] swizzled
  __shared__ u16 __align__(16) Vls[2][256 * 64];  // [buf][c][n] swizzled
  __shared__ u16 __align__(16) Pls[64 * 72];      // P^T [m][n], stride 72
  __shared__ float pmax[2][64];
  __shared__ float psum[2][64];

  const int t = threadIdx.x, w = t >> 6, lane = t & 63;
  const int l31 = lane & 31, l5 = lane >> 5;
  const int nh = w & 1, mh = w >> 1;

  // XCD swizzle: 2 XCDs per batch -> K+V (4MB/batch) stays in per-XCD L2.
  const int linear = blockIdx.x;
  const int xcd = linear & 7, slot = linear >> 3;  // slot in [0,32)
  const int b = xcd >> 1;
  const int mblk = (xcd & 1) * 32 + slot;  // [0,64)
  const int m0 = mblk * 64;

  const u16* Qb = q_t + (size_t)b * NSEQ * CD;
  const u16* Kb = k_t + (size_t)b * NSEQ * CD;
  const u16* Vb = v_ + (size_t)b * CD * NSEQ;

  // Q fragments in registers (B-operand for S): rows m0+mh*32+l31, K=256
  short8 qf[16];
#pragma unroll
  for (int kc = 0; kc < 16; ++kc)
    qf[kc] = *(const short8*)(Qb + (size_t)(m0 + mh * 32 + l31) * CD + kc * 16 + l5 * 8);

  const int kr = w * 16;                 // this wave's K-row base (2 rows/DMA)
  const int vrb = w * 64;                // this wave's V-row base (8 rows/DMA)
  const int vr_lane = lane >> 3, vc_lane = lane & 7;

  // stage tile 0 into buf 0
#pragma unroll
  for (int j = 0; j < 8; ++j) {
    int r = kr + j * 2 + l5;
    async16(Kb + (size_t)r * CD + ((l31 ^ (r & 7)) * 8),
            &Kls[0][(kr + j * 2) * 256]);
    int rv = vrb + j * 8 + vr_lane;
    async16(Vb + (size_t)rv * NSEQ + ((vc_lane ^ (rv & 7)) * 8),
            &Vls[0][(vrb + j * 8) * 64]);
  }

  float mst = -3.0e38f, lst = 0.f;
  f32x16 oa[4];  // oa[ct]: c = nh*128 + ct*32 + rowmap, m = m0 + mh*32 + l31
#pragma unroll
  for (int i = 0; i < 4; ++i)
#pragma unroll
    for (int r = 0; r < 16; ++r) oa[i][r] = 0.f;

  for (int tt = 0; tt < 64; ++tt) {
    const int cur = tt & 1;
    // top drain: tile tt's DMA complete in buf[cur]; prior-iter reads done
    __builtin_amdgcn_s_waitcnt(0);
    __syncthreads();
    // prefetch tile tt+1 into the OTHER buffer (no reader until next drain)
    if (tt + 1 < 64) {
      const int n0 = (tt + 1) * 64;
      const int nxt = cur ^ 1;
#pragma unroll
      for (int j = 0; j < 8; ++j) {
        int r = kr + j * 2 + l5;
        async16(Kb + (size_t)(n0 + r) * CD + ((l31 ^ (r & 7)) * 8),
                &Kls[nxt][(kr + j * 2) * 256]);
        int rv = vrb + j * 8 + vr_lane;
        async16(Vb + (size_t)rv * NSEQ + n0 + ((vc_lane ^ (rv & 7)) * 8),
                &Vls[nxt][(vrb + j * 8) * 64]);
      }
    }
    // ---- S = K . Q^T : wave's 32n x 32m, K=256 ----
    f32x16 s;
#pragma unroll
    for (int i = 0; i < 16; ++i) s[i] = 0.f;
    const int rk = nh * 32 + l31;
#pragma unroll
    for (int kc = 0; kc < 16; ++kc) {
      short8 a =
          *(const short8*)(&Kls[cur][rk * 256 + (((kc * 2 + l5) ^ (rk & 7)) * 8)]);
      s = MFMA32(a, qf[kc], s, 0, 0, 0);
    }
    // ---- per-m max over this wave's 32 n-rows (l5 halves merge via xor32) --
    float rm = s[0];
#pragma unroll
    for (int i = 1; i < 16; ++i) rm = fmaxf(rm, s[i]);
    rm = fmaxf(rm, __shfl_xor(rm, 32));
    if (lane < 32) pmax[nh][mh * 32 + lane] = rm;
    __syncthreads();  // B2
    float rb = fmaxf(pmax[0][mh * 32 + l31], pmax[1][mh * 32 + l31]);
    float mnew = fmaxf(mst, rb * CF);
    float al = exp2f(mst - mnew);
    mst = mnew;
    // ---- p = exp2(s*CF - mnew); write P^T[m][n]; partial sums ----
    float ls = 0.f;
#pragma unroll
    for (int g = 0; g < 4; ++g) {
      short4v pk;
#pragma unroll
      for (int r = 0; r < 4; ++r) {
        float p = exp2f(s[g * 4 + r] * CF - mnew);
        ls += p;
        pk[r] = (short)f2bf(p);
      }
      // n_local = nh*32 + r + 8g + 4*l5  (C/D row map, m74/m101)
      *(short4v*)(Pls + (mh * 32 + l31) * 72 + nh * 32 + g * 8 + l5 * 4) = pk;
    }
    ls += __shfl_xor(ls, 32);
    if (lane < 32) psum[nh][mh * 32 + lane] = ls;
    __syncthreads();  // B3
    lst = lst * al + psum[0][mh * 32 + l31] + psum[1][mh * 32 + l31];
    // ---- rescale own-m O (per-lane scalar), then O += V . P ----
#pragma unroll
    for (int i = 0; i < 4; ++i)
#pragma unroll
      for (int r = 0; r < 16; ++r) oa[i][r] *= al;
#pragma unroll
    for (int nb = 0; nb < 4; ++nb) {
      short8 pf = *(const short8*)(Pls + (mh * 32 + l31) * 72 + nb * 16 + l5 * 8);
#pragma unroll
      for (int ct = 0; ct < 4; ++ct) {
        int c = nh * 128 + ct * 32 + l31;
        short8 vf =
            *(const short8*)(&Vls[cur][c * 64 + (((nb * 2 + l5) ^ (c & 7)) * 8)]);
        oa[ct] = MFMA32(vf, pf, oa[ct], 0, 0, 0);
      }
    }
    // no bottom barrier needed: next top drain orders P reuse and buf swap
  }

  // ---- finalize: O /= l (per-lane); store o_t (n=query, c) bf16 ----
  float inv = 1.0f / lst;
  u16* dst = o_t + ((size_t)b * NSEQ + m0 + mh * 32 + l31) * CD;
#pragma unroll
  for (int ct = 0; ct < 4; ++ct)
#pragma unroll
    for (int g = 0; g < 4; ++g) {
      short4v pk;
#pragma unroll
      for (int r = 0; r < 4; ++r) pk[r] = (short)f2bf(oa[ct][g * 4 + r] * inv);
      *(short4v*)(dst + nh * 128 + ct * 32 + g * 8 + l5 * 4) = pk;
    }
}

// ---------------------------------------------------------------------------
// out projection: out[b][o][n] = sum_c Wo[o][c] * o_t[n][c] + out_b[o]  (f32)
// grid (64, 4, 4), block 256. Single-shot DMA staging (no reuse, no hazard).
// ---------------------------------------------------------------------------
__global__ __launch_bounds__(256, 2) void out_gemm3(
    const u16* __restrict__ wo, const float* __restrict__ out_b,
    const u16* __restrict__ o_t, float* __restrict__ out) {
  __shared__ u16 __align__(16) Wls[64 * 256];
  __shared__ u16 __align__(16) Bls[64 * 256];
  const int t = threadIdx.x, w = t >> 6, lane = t & 63;
  const int l31 = lane & 31, l5 = lane >> 5;
  const int oh = w & 1, nh2 = w >> 1;
  const int n0 = blockIdx.x * 64, o0 = blockIdx.y * 64, b = blockIdx.z;
  const u16* Ob = o_t + (size_t)b * NSEQ * CD;
#pragma unroll
  for (int j = 0; j < 8; ++j) {
    int r = w * 16 + j * 2 + l5;
    async16(wo + (size_t)(o0 + r) * CD + ((l31 ^ (r & 7)) * 8),
            Wls + (w * 16 + j * 2) * 256);
    async16(Ob + (size_t)(n0 + r) * CD + ((l31 ^ (r & 7)) * 8),
            Bls + (w * 16 + j * 2) * 256);
  }
  __builtin_amdgcn_s_waitcnt(0);
  __syncthreads();
  f32x16 acc;
#pragma unroll
  for (int i = 0; i < 16; ++i) acc[i] = 0.f;
  const int ra = oh * 32 + l31, rb = nh2 * 32 + l31;
#pragma unroll
  for (int kc = 0; kc < 16; ++kc) {
    short8 a = *(const short8*)(Wls + ra * 256 + (((kc * 2 + l5) ^ (ra & 7)) * 8));
    short8 bb = *(const short8*)(Bls + rb * 256 + (((kc * 2 + l5) ^ (rb & 7)) * 8));
    acc = MFMA32(a, bb, acc, 0, 0, 0);
  }
  const int n_g = n0 + nh2 * 32 + l31;
#pragma unroll
  for (int g = 0; g < 4; ++g) {
    float4 bv = *(const float4*)(out_b + o0 + oh * 32 + g * 8 + l5 * 4);
    const float* bp = (const float*)&bv;
#pragma unroll
    for (int r = 0; r < 4; ++r) {
      int o = o0 + oh * 32 + g * 8 + l5 * 4 + r;
      out[((size_t)b * CD + o) * NSEQ + n_g] = acc[g * 4 + r] + bp[r];
    }
  }
}

// ---------------------------------------------------------------------------
extern "C" void kernel_launch(void* const* d_in, const int* in_sizes, int n_in,
                              void* d_out, int out_size, void* d_ws,
                              size_t ws_size, hipStream_t stream) {
  const float* x = (const float*)d_in[0];
  const float* qkv_w = (const float*)d_in[1];
  const float* qkv_b = (const float*)d_in[2];
  const float* out_w = (const float*)d_in[3];
  const float* out_b = (const float*)d_in[4];
  float* out = (float*)d_out;

  const size_t SZ = (size_t)4 * NSEQ * CD;  // elems per (b,4096,256) bf16
  u16* x_t = (u16*)d_ws;
  u16* q_t = x_t + SZ;
  u16* k_t = q_t + SZ;
  u16* v_ = k_t + SZ;
  u16* o_t = v_ + SZ;
  u16* wq = o_t + SZ;            // 768*256
  u16* wo = wq + 768 * CD;       // 256*256

  dim3 blk(256);
  cast_w<<<dim3(768), blk, 0, stream>>>(qkv_w, out_w, wq, wo);
  xpose<<<dim3(64, 4, 4), blk, 0, stream>>>(x, x_t);
  qkv_gemm2<<<dim3(64, 12, 4), blk, 0, stream>>>(wq, qkv_b, x_t, q_t, k_t, v_);
  flash4<<<dim3(256), blk, 0, stream>>>(q_t, k_t, v_, o_t);
  out_gemm3<<<dim3(64, 4, 4), blk, 0, stream>>>(wo, out_b, o_t, out);
}

// Round 7
// 217.477 us; speedup vs baseline: 8.2871x; 1.2554x over previous
//
#include <hip/hip_runtime.h>

typedef unsigned short u16;
typedef unsigned int u32;
typedef __attribute__((ext_vector_type(8))) short short8;   // 8 x bf16 frag
typedef __attribute__((ext_vector_type(4))) short short4v;  // 4 x bf16 pack
typedef __attribute__((ext_vector_type(16))) float f32x16;  // 32x32 acc

#define MFMA32 __builtin_amdgcn_mfma_f32_32x32x16_bf16

#define NSEQ 4096
#define CD 256
// (1/sqrt(256)) * log2(e) = 0.0625 * 1.4426950408889634  -- EXACT.
#define CF 0.09016844005556021f

__device__ __forceinline__ u16 f2bf(float f) {
  u32 u = __float_as_uint(f);
  u += 0x7fffu + ((u >> 16) & 1u);  // RNE
  return (u16)(u >> 16);
}
__device__ __forceinline__ float bf2f(short s) {
  return __uint_as_float(((u32)(u16)s) << 16);
}
// async global -> LDS DMA, 16B per lane; LDS dest = wave-uniform base + lane*16
__device__ __forceinline__ void async16(const void* g, void* l) {
  __builtin_amdgcn_global_load_lds(
      (const __attribute__((address_space(1))) u32*)g,
      (__attribute__((address_space(3))) u32*)l, 16, 0, 0);
}

// ---------------------------------------------------------------------------
// cast weights fp32 -> bf16
// ---------------------------------------------------------------------------
__global__ void cast_w(const float* __restrict__ qkv_w,
                       const float* __restrict__ out_w, u16* __restrict__ wq,
                       u16* __restrict__ wo) {
  int idx = blockIdx.x * 256 + threadIdx.x;
  if (idx < 768 * CD) wq[idx] = f2bf(qkv_w[idx]);
  if (idx < CD * CD) wo[idx] = f2bf(out_w[idx]);
}

// ---------------------------------------------------------------------------
// transpose-cast x: (b, 256, 4096) f32 -> x_t (b, 4096, 256) bf16
// ---------------------------------------------------------------------------
__global__ __launch_bounds__(256) void xpose(const float* __restrict__ x,
                                             u16* __restrict__ x_t) {
  __shared__ float tile[64][65];
  const int t = threadIdx.x;
  const int b = blockIdx.z;
  const int n0 = blockIdx.x * 64, c0 = blockIdx.y * 64;
  const float* xb = x + (size_t)b * CD * NSEQ;
  const int cr = t >> 4, nc4 = (t & 15) * 4;
#pragma unroll
  for (int i = 0; i < 4; ++i) {
    int c = cr + 16 * i;
    float4 v = *(const float4*)(xb + (size_t)(c0 + c) * NSEQ + n0 + nc4);
    tile[c][nc4 + 0] = v.x;
    tile[c][nc4 + 1] = v.y;
    tile[c][nc4 + 2] = v.z;
    tile[c][nc4 + 3] = v.w;
  }
  __syncthreads();
  const int n = t & 63, cc = (t >> 6) * 16;
  u16* dst = x_t + (size_t)b * NSEQ * CD + (size_t)(n0 + n) * CD + c0 + cc;
#pragma unroll
  for (int j = 0; j < 4; ++j) {
    short4v pv;
#pragma unroll
    for (int r = 0; r < 4; ++r) pv[r] = (short)f2bf(tile[cc + 4 * j + r][n]);
    *(short4v*)(dst + 4 * j) = pv;
  }
}

// ---------------------------------------------------------------------------
// QKV projection, 32x32x16 MFMA, LDS-staged W and X tiles (XOR-swizzled, DMA).
// D[o][n] = sum_c W[o][c] x_t[n][c] + bias. grid (64, 12, 4), block 256.
// ---------------------------------------------------------------------------
__global__ __launch_bounds__(256, 2) void qkv_gemm2(
    const u16* __restrict__ wq, const float* __restrict__ qkv_b,
    const u16* __restrict__ x_t, u16* __restrict__ q_t, u16* __restrict__ k_t,
    u16* __restrict__ v_) {
  __shared__ u16 __align__(16) Wls[64 * 256];
  __shared__ u16 __align__(16) Bls[64 * 256];
  const int t = threadIdx.x, w = t >> 6, lane = t & 63;
  const int l31 = lane & 31, l5 = lane >> 5;
  const int oh = w & 1, nh2 = w >> 1;
  const int n0 = blockIdx.x * 64, o0 = blockIdx.y * 64, b = blockIdx.z;
  const u16* Xb = x_t + (size_t)b * NSEQ * CD;
#pragma unroll
  for (int j = 0; j < 8; ++j) {
    int r = w * 16 + j * 2 + l5;
    async16(wq + (size_t)(o0 + r) * CD + ((l31 ^ (r & 7)) * 8),
            Wls + (w * 16 + j * 2) * 256);
    async16(Xb + (size_t)(n0 + r) * CD + ((l31 ^ (r & 7)) * 8),
            Bls + (w * 16 + j * 2) * 256);
  }
  __builtin_amdgcn_s_waitcnt(0);
  __syncthreads();
  f32x16 acc;
#pragma unroll
  for (int i = 0; i < 16; ++i) acc[i] = 0.f;
  const int ra = oh * 32 + l31, rb = nh2 * 32 + l31;
#pragma unroll
  for (int kc = 0; kc < 16; ++kc) {
    short8 a = *(const short8*)(Wls + ra * 256 + (((kc * 2 + l5) ^ (ra & 7)) * 8));
    short8 bb = *(const short8*)(Bls + rb * 256 + (((kc * 2 + l5) ^ (rb & 7)) * 8));
    acc = MFMA32(a, bb, acc, 0, 0, 0);
  }
  const int n_g = n0 + nh2 * 32 + l31;
  const int otype = blockIdx.y >> 2;  // 0=Q 1=K 2=V
  if (otype < 2) {
    u16* dst = (otype == 0 ? q_t : k_t) + (size_t)b * NSEQ * CD + (size_t)n_g * CD;
    const int cb0 = o0 - otype * 256 + oh * 32;
#pragma unroll
    for (int g = 0; g < 4; ++g) {
      float4 bv = *(const float4*)(qkv_b + o0 + oh * 32 + g * 8 + l5 * 4);
      const float* bp = (const float*)&bv;
      short4v pk;
#pragma unroll
      for (int r = 0; r < 4; ++r) pk[r] = (short)f2bf(acc[g * 4 + r] + bp[r]);
      *(short4v*)(dst + cb0 + g * 8 + l5 * 4) = pk;
    }
  } else {
    u16* dst = v_ + (size_t)b * CD * NSEQ;
#pragma unroll
    for (int g = 0; g < 4; ++g) {
      float4 bv = *(const float4*)(qkv_b + o0 + oh * 32 + g * 8 + l5 * 4);
      const float* bp = (const float*)&bv;
#pragma unroll
      for (int r = 0; r < 4; ++r) {
        int c = o0 - 512 + oh * 32 + g * 8 + l5 * 4 + r;
        dst[(size_t)c * NSEQ + n_g] = f2bf(acc[g * 4 + r] + bp[r]);
      }
    }
  }
}

// ---------------------------------------------------------------------------
// Flash attention v5: 512-thread blocks (8 waves = 2/SIMD), m-tile 128 with
// two 4-wave groups SHARING the staged K/V tiles, key-split 2 (grid 256),
// double-buffered DMA staging, alpha-skip O-rescale.
// Wave (g = w>>2, nh = w&1, mh = (w>>1)&1): m-cols = m0 + g*64 + mh*32 + l31.
//   S : [n-half nh (32)] x [own 32 m], K=256.   D col = m.
//   PV: [c-half nh (128)] x [own 32 m] over 64-key tile.  D col = m.
// Emits per-half normalized O (bf16) + (m,l); merge happens in out_gemm4.
// ---------------------------------------------------------------------------
__global__ __launch_bounds__(512, 2) void flash5(const u16* __restrict__ q_t,
                                                 const u16* __restrict__ k_t,
                                                 const u16* __restrict__ v_,
                                                 u16* __restrict__ opart,
                                                 float2* __restrict__ ml) {
  __shared__ u16 __align__(16) Kls[2][64 * 256];  // [buf][n][c] swizzled
  __shared__ u16 __align__(16) Vls[2][256 * 64];  // [buf][c][n] swizzled
  __shared__ u16 __align__(16) Pls[128 * 72];     // P^T [m][n], stride 72
  __shared__ float pmax[2][128];
  __shared__ float psum[2][128];

  const int t = threadIdx.x, w = t >> 6, lane = t & 63;
  const int l31 = lane & 31, l5 = lane >> 5;
  const int g = w >> 2, nh = w & 1, mh = (w >> 1) & 1;

  // XCD swizzle: 2 XCDs per batch; per XCD one key-half -> 2MB K/V in its L2.
  const int linear = blockIdx.x;
  const int xcd = linear & 7, slot = linear >> 3;  // slot in [0,32)
  const int b = xcd >> 1;
  const int sub = (xcd & 1) * 32 + slot;  // [0,64)
  const int mblk = sub & 31, half = sub >> 5;
  const int m0 = mblk * 128;
  const int nbase = half * 2048;

  const u16* Qb = q_t + (size_t)b * NSEQ * CD;
  const u16* Kb = k_t + (size_t)b * NSEQ * CD;
  const u16* Vb = v_ + (size_t)b * CD * NSEQ;

  const int lm = g * 64 + mh * 32 + l31;  // m-index within the 128-tile
  const int mrow = m0 + lm;               // global query index

  // Q fragments in registers (B-operand for S), K=256
  short8 qf[16];
#pragma unroll
  for (int kc = 0; kc < 16; ++kc)
    qf[kc] = *(const short8*)(Qb + (size_t)mrow * CD + kc * 16 + l5 * 8);

  const int kr = w * 8;   // this wave's K staging rows (2 rows per DMA, 4 DMA)
  const int vrb = w * 32; // this wave's V staging rows (8 rows per DMA, 4 DMA)
  const int vr_lane = lane >> 3, vc_lane = lane & 7;

  // stage tile 0 into buf 0
#pragma unroll
  for (int j = 0; j < 4; ++j) {
    int r = kr + j * 2 + l5;
    async16(Kb + (size_t)(nbase + r) * CD + ((l31 ^ (r & 7)) * 8),
            &Kls[0][(kr + j * 2) * 256]);
    int rv = vrb + j * 8 + vr_lane;
    async16(Vb + (size_t)rv * NSEQ + nbase + ((vc_lane ^ (rv & 7)) * 8),
            &Vls[0][(vrb + j * 8) * 64]);
  }

  float mst = -3.0e38f, lst = 0.f;
  f32x16 oa[4];  // oa[ct]: c = nh*128 + ct*32 + rowmap, m = mrow
#pragma unroll
  for (int i = 0; i < 4; ++i)
#pragma unroll
    for (int r = 0; r < 16; ++r) oa[i][r] = 0.f;

  for (int tt = 0; tt < 32; ++tt) {
    const int cur = tt & 1;
    // top drain: tile tt's DMA complete in buf[cur]; prior-iter reads done
    __builtin_amdgcn_s_waitcnt(0);
    __syncthreads();
    // prefetch tile tt+1 into the other buffer
    if (tt + 1 < 32) {
      const int n0 = nbase + (tt + 1) * 64;
      const int nxt = cur ^ 1;
#pragma unroll
      for (int j = 0; j < 4; ++j) {
        int r = kr + j * 2 + l5;
        async16(Kb + (size_t)(n0 + r) * CD + ((l31 ^ (r & 7)) * 8),
                &Kls[nxt][(kr + j * 2) * 256]);
        int rv = vrb + j * 8 + vr_lane;
        async16(Vb + (size_t)rv * NSEQ + n0 + ((vc_lane ^ (rv & 7)) * 8),
                &Vls[nxt][(vrb + j * 8) * 64]);
      }
    }
    // ---- S = K . Q^T : wave's 32n x 32m, K=256 ----
    f32x16 s;
#pragma unroll
    for (int i = 0; i < 16; ++i) s[i] = 0.f;
    const int rk = nh * 32 + l31;
#pragma unroll
    for (int kc = 0; kc < 16; ++kc) {
      short8 a =
          *(const short8*)(&Kls[cur][rk * 256 + (((kc * 2 + l5) ^ (rk & 7)) * 8)]);
      s = MFMA32(a, qf[kc], s, 0, 0, 0);
    }
    // ---- per-m max over wave's 32 n-rows ----
    float rm = s[0];
#pragma unroll
    for (int i = 1; i < 16; ++i) rm = fmaxf(rm, s[i]);
    rm = fmaxf(rm, __shfl_xor(rm, 32));
    if (lane < 32) pmax[nh][g * 64 + mh * 32 + lane] = rm;
    __syncthreads();  // B2
    float rb = fmaxf(pmax[0][lm], pmax[1][lm]);
    float mnew = fmaxf(mst, rb * CF);
    float al = exp2f(mst - mnew);
    mst = mnew;
    // ---- p = exp2(s*CF - mnew); write P^T[m][n]; partial sums ----
    float ls = 0.f;
#pragma unroll
    for (int gg = 0; gg < 4; ++gg) {
      short4v pk;
#pragma unroll
      for (int r = 0; r < 4; ++r) {
        float p = exp2f(s[gg * 4 + r] * CF - mnew);
        ls += p;
        pk[r] = (short)f2bf(p);
      }
      // n_local = nh*32 + r + 8*gg + 4*l5  (C/D row map)
      *(short4v*)(Pls + lm * 72 + nh * 32 + gg * 8 + l5 * 4) = pk;
    }
    ls += __shfl_xor(ls, 32);
    if (lane < 32) psum[nh][g * 64 + mh * 32 + lane] = ls;
    __syncthreads();  // B3
    lst = lst * al + psum[0][lm] + psum[1][lm];
    // ---- rescale own-m O only when the max actually moved (rare) ----
    if (__ballot(al != 1.0f)) {
#pragma unroll
      for (int i = 0; i < 4; ++i)
#pragma unroll
        for (int r = 0; r < 16; ++r) oa[i][r] *= al;
    }
    // ---- O += V . P : c-half nh (4 subtiles), own m ----
#pragma unroll
    for (int nb = 0; nb < 4; ++nb) {
      short8 pf = *(const short8*)(Pls + lm * 72 + nb * 16 + l5 * 8);
#pragma unroll
      for (int ct = 0; ct < 4; ++ct) {
        int c = nh * 128 + ct * 32 + l31;
        short8 vf =
            *(const short8*)(&Vls[cur][c * 64 + (((nb * 2 + l5) ^ (c & 7)) * 8)]);
        oa[ct] = MFMA32(vf, pf, oa[ct], 0, 0, 0);
      }
    }
  }

  // ---- finalize: per-half normalized O -> bf16; (m,l) for the merge ----
  float inv = 1.0f / lst;
  u16* dst = opart + ((size_t)(half * 4 + b) * NSEQ + mrow) * CD;
#pragma unroll
  for (int ct = 0; ct < 4; ++ct)
#pragma unroll
    for (int gg = 0; gg < 4; ++gg) {
      short4v pk;
#pragma unroll
      for (int r = 0; r < 4; ++r) pk[r] = (short)f2bf(oa[ct][gg * 4 + r] * inv);
      *(short4v*)(dst + nh * 128 + ct * 32 + gg * 8 + l5 * 4) = pk;
    }
  if (nh == 0 && lane < 32)
    ml[(size_t)(half * 4 + b) * NSEQ + m0 + g * 64 + mh * 32 + lane] =
        make_float2(mst, lst);
}

// ---------------------------------------------------------------------------
// out projection + split-key merge folded into B-tile staging.
// out[b][o][n] = sum_c Wo[o][c] * O_merged[n][c] + out_b[o]  (f32)
// grid (64, 4, 4), block 256.
// ---------------------------------------------------------------------------
__global__ __launch_bounds__(256, 2) void out_gemm4(
    const u16* __restrict__ wo, const float* __restrict__ out_b,
    const u16* __restrict__ opart, const float2* __restrict__ ml,
    float* __restrict__ out) {
  __shared__ u16 __align__(16) Wls[64 * 256];
  __shared__ u16 __align__(16) Bls[64 * 256];
  const int t = threadIdx.x, w = t >> 6, lane = t & 63;
  const int l31 = lane & 31, l5 = lane >> 5;
  const int oh = w & 1, nh2 = w >> 1;
  const int n0 = blockIdx.x * 64, o0 = blockIdx.y * 64, b = blockIdx.z;
#pragma unroll
  for (int j = 0; j < 8; ++j) {
    int r = w * 16 + j * 2 + l5;
    async16(wo + (size_t)(o0 + r) * CD + ((l31 ^ (r & 7)) * 8),
            Wls + (w * 16 + j * 2) * 256);
  }
  const u16* O1 = opart + (size_t)b * NSEQ * CD;
  const u16* O2 = opart + (size_t)(4 + b) * NSEQ * CD;
  const float2* ml1 = ml + (size_t)b * NSEQ;
  const float2* ml2 = ml + (size_t)(4 + b) * NSEQ;
#pragma unroll
  for (int i = 0; i < 8; ++i) {
    int idx = i * 256 + t;
    int r = idx >> 5, p = idx & 31;
    int n = n0 + r;
    float2 s1 = ml1[n], s2 = ml2[n];
    float M = fmaxf(s1.x, s2.x);
    float w1 = s1.y * exp2f(s1.x - M), w2 = s2.y * exp2f(s2.x - M);
    float inv = 1.0f / (w1 + w2);
    w1 *= inv;
    w2 *= inv;
    short8 x1 = *(const short8*)(O1 + (size_t)n * CD + p * 8);
    short8 x2 = *(const short8*)(O2 + (size_t)n * CD + p * 8);
    short8 om;
#pragma unroll
    for (int e = 0; e < 8; ++e)
      om[e] = (short)f2bf(w1 * bf2f(x1[e]) + w2 * bf2f(x2[e]));
    *(short8*)(Bls + r * 256 + ((p ^ (r & 7)) * 8)) = om;
  }
  __builtin_amdgcn_s_waitcnt(0);
  __syncthreads();
  f32x16 acc;
#pragma unroll
  for (int i = 0; i < 16; ++i) acc[i] = 0.f;
  const int ra = oh * 32 + l31, rb = nh2 * 32 + l31;
#pragma unroll
  for (int kc = 0; kc < 16; ++kc) {
    short8 a = *(const short8*)(Wls + ra * 256 + (((kc * 2 + l5) ^ (ra & 7)) * 8));
    short8 bb = *(const short8*)(Bls + rb * 256 + (((kc * 2 + l5) ^ (rb & 7)) * 8));
    acc = MFMA32(a, bb, acc, 0, 0, 0);
  }
  const int n_g = n0 + nh2 * 32 + l31;
#pragma unroll
  for (int g = 0; g < 4; ++g) {
    float4 bv = *(const float4*)(out_b + o0 + oh * 32 + g * 8 + l5 * 4);
    const float* bp = (const float*)&bv;
#pragma unroll
    for (int r = 0; r < 4; ++r) {
      int o = o0 + oh * 32 + g * 8 + l5 * 4 + r;
      out[((size_t)b * CD + o) * NSEQ + n_g] = acc[g * 4 + r] + bp[r];
    }
  }
}

// ---------------------------------------------------------------------------
extern "C" void kernel_launch(void* const* d_in, const int* in_sizes, int n_in,
                              void* d_out, int out_size, void* d_ws,
                              size_t ws_size, hipStream_t stream) {
  const float* x = (const float*)d_in[0];
  const float* qkv_w = (const float*)d_in[1];
  const float* qkv_b = (const float*)d_in[2];
  const float* out_w = (const float*)d_in[3];
  const float* out_b = (const float*)d_in[4];
  float* out = (float*)d_out;

  const size_t SZ = (size_t)4 * NSEQ * CD;  // elems per (b,4096,256) bf16
  u16* x_t = (u16*)d_ws;
  u16* q_t = x_t + SZ;
  u16* k_t = q_t + SZ;
  u16* v_ = k_t + SZ;
  u16* opart = v_ + SZ;              // 2 key-halves, 2*SZ
  u16* wq = opart + 2 * SZ;          // 768*256
  u16* wo = wq + 768 * CD;           // 256*256
  float2* ml = (float2*)(wo + CD * CD);  // 2*4*4096 float2

  dim3 blk(256);
  cast_w<<<dim3(768), blk, 0, stream>>>(qkv_w, out_w, wq, wo);
  xpose<<<dim3(64, 4, 4), blk, 0, stream>>>(x, x_t);
  qkv_gemm2<<<dim3(64, 12, 4), blk, 0, stream>>>(wq, qkv_b, x_t, q_t, k_t, v_);
  flash5<<<dim3(256), dim3(512), 0, stream>>>(q_t, k_t, v_, opart, ml);
  out_gemm4<<<dim3(64, 4, 4), blk, 0, stream>>>(wo, out_b, opart, ml, out);
}